// Round 1
// baseline (1878.860 us; speedup 1.0000x reference)
//
#include <hip/hip_runtime.h>
#include <cstddef>
#include <cstdint>

// Problem constants (from reference): B=2, S=2048, D_MODEL=1024, H=16, DH=64
#define B_ 2
#define S_ 2048
#define DM_ 1024
#define H_ 16
#define DH_ 64
#define NEGV (-1e12f)

// ---------------------------------------------------------------------------
// Tiled fp32 GEMM + bias: C[M,N] = A[M,K] @ W[K,N] + bias[N]
// 64x64 tile, BK=16, 256 threads, 4x4 per thread.
// ---------------------------------------------------------------------------
__global__ __launch_bounds__(256) void gemm_bias_kernel(
    const float* __restrict__ A, const float* __restrict__ W,
    const float* __restrict__ bias, float* __restrict__ C,
    int M, int N, int K)
{
    __shared__ float As[16][66];  // k-major, padded (2-way max on r/w)
    __shared__ float Bs[16][64];  // k-major

    const int tid = threadIdx.x;
    const int m0 = blockIdx.y * 64;
    const int n0 = blockIdx.x * 64;
    const int tx = tid & 15;      // output col quad
    const int ty = tid >> 4;      // output row quad

    const int arow = tid >> 2, akq = tid & 3;   // A-tile load mapping
    const int bk   = tid >> 4, bnq = tid & 15;  // B-tile load mapping

    float acc[4][4];
#pragma unroll
    for (int i = 0; i < 4; ++i)
#pragma unroll
        for (int j = 0; j < 4; ++j) acc[i][j] = 0.f;

    for (int k0 = 0; k0 < K; k0 += 16) {
        // issue global loads first (latency overlaps previous tile's tail)
        const float4 a4 = *(const float4*)(A + (size_t)(m0 + arow) * K + k0 + akq * 4);
        const float4 b4 = *(const float4*)(W + (size_t)(k0 + bk) * N + n0 + bnq * 4);
        __syncthreads();  // previous iteration's LDS reads complete
        As[akq * 4 + 0][arow] = a4.x;
        As[akq * 4 + 1][arow] = a4.y;
        As[akq * 4 + 2][arow] = a4.z;
        As[akq * 4 + 3][arow] = a4.w;
        *(float4*)&Bs[bk][bnq * 4] = b4;
        __syncthreads();
#pragma unroll
        for (int kk = 0; kk < 16; ++kk) {
            float a[4], b[4];
#pragma unroll
            for (int i = 0; i < 4; ++i) a[i] = As[kk][ty * 4 + i];
#pragma unroll
            for (int j = 0; j < 4; ++j) b[j] = Bs[kk][tx * 4 + j];
#pragma unroll
            for (int i = 0; i < 4; ++i)
#pragma unroll
                for (int j = 0; j < 4; ++j) acc[i][j] += a[i] * b[j];
        }
    }

    const float4 bia = *(const float4*)(bias + n0 + tx * 4);
#pragma unroll
    for (int i = 0; i < 4; ++i) {
        const int m = m0 + ty * 4 + i;
        float4 o;
        o.x = acc[i][0] + bia.x;
        o.y = acc[i][1] + bia.y;
        o.z = acc[i][2] + bia.z;
        o.w = acc[i][3] + bia.w;
        *(float4*)(C + (size_t)m * N + n0 + tx * 4) = o;
    }
}

// ---------------------------------------------------------------------------
// RoPE (in place on Q and K).
// out[2i]   = t[2i]*pos[2i+1] - t[2i+1]*pos[2i]
// out[2i+1] = t[2i+1]*pos[2i+1] + t[2i]*pos[2i]
// ---------------------------------------------------------------------------
__global__ __launch_bounds__(256) void rope_kernel(
    float* __restrict__ Q, float* __restrict__ K, const float* __restrict__ pos)
{
    const int idx = blockIdx.x * blockDim.x + threadIdx.x;  // pair index
    // total pairs = B*S*H*(DH/2) = 2*2048*16*32 = 2^21
    const int i = idx & 31;
    const int h = (idx >> 5) & 15;
    const int s = (idx >> 9) & 2047;
    const int b = idx >> 20;

    const float sn = pos[s * DH_ + 2 * i];
    const float c  = pos[s * DH_ + 2 * i + 1];
    const size_t base = ((size_t)(b * S_ + s)) * DM_ + h * DH_ + 2 * i;

    float2 q = *(float2*)(Q + base);
    float2 k = *(float2*)(K + base);
    float2 qo, ko;
    qo.x = q.x * c - q.y * sn;
    qo.y = q.y * c + q.x * sn;
    ko.x = k.x * c - k.y * sn;
    ko.y = k.y * c + k.x * sn;
    *(float2*)(Q + base) = qo;
    *(float2*)(K + base) = ko;
}

// ---------------------------------------------------------------------------
// Flash-style fp32 attention.
// Block: one (b,h) and 16 query rows. K/V tiles of 64. Online softmax.
// Roles (per-thread, constant across tiles):
//   score/O-element mapping: e = tid + 256*i -> m = e&15, n/d = e>>4
//   reduction mapping:       rrow = tid>>4, rtx = tid&15
// ---------------------------------------------------------------------------
__global__ __launch_bounds__(256) void attn_kernel(
    const float* __restrict__ Q, const float* __restrict__ K,
    const float* __restrict__ V, const int* __restrict__ vmask,
    float* __restrict__ O)
{
    __shared__ float Qs[16][65];
    __shared__ float Ks[64][65];
    __shared__ float Vs[64][65];
    __shared__ float Ps[16][65];
    __shared__ float scale_s[16];
    __shared__ float linv_s[16];

    const int tid = threadIdx.x;
    const int bid = blockIdx.x;           // ((b*H + h)*128 + rchunk)
    const int rchunk = bid & 127;
    const int h = (bid >> 7) & 15;
    const int b = bid >> 11;
    const int s0 = rchunk * 16;
    const size_t base_bh = (size_t)b * S_ * DM_ + h * DH_;

    // load Q tile: 16 rows x 64 cols
    {
        const int row = tid >> 4, cq = tid & 15;
        const float4 q4 = *(const float4*)(Q + base_bh + (size_t)(s0 + row) * DM_ + cq * 4);
        Qs[row][cq * 4 + 0] = q4.x;
        Qs[row][cq * 4 + 1] = q4.y;
        Qs[row][cq * 4 + 2] = q4.z;
        Qs[row][cq * 4 + 3] = q4.w;
    }

    const int rrow = tid >> 4, rtx = tid & 15;  // reduction role
    const int orow = tid & 15, ocol = tid >> 4; // score/O role

    float m_run = -1e30f, l_run = 0.f;          // stats for row rrow
    float acc[4] = {0.f, 0.f, 0.f, 0.f};        // O[orow][ocol + 16*i]

    for (int kt = 0; kt < S_ / 64; ++kt) {
        __syncthreads();  // previous tile's Ks/Vs/Ps reads done
        // load K,V tiles: 64 rows x 64 cols each
#pragma unroll
        for (int i = 0; i < 4; ++i) {
            const int t = tid + 256 * i;
            const int row = t >> 4, cq = t & 15;
            const size_t g = base_bh + (size_t)(kt * 64 + row) * DM_ + cq * 4;
            const float4 k4 = *(const float4*)(K + g);
            const float4 v4 = *(const float4*)(V + g);
            Ks[row][cq * 4 + 0] = k4.x; Ks[row][cq * 4 + 1] = k4.y;
            Ks[row][cq * 4 + 2] = k4.z; Ks[row][cq * 4 + 3] = k4.w;
            Vs[row][cq * 4 + 0] = v4.x; Vs[row][cq * 4 + 1] = v4.y;
            Vs[row][cq * 4 + 2] = v4.z; Vs[row][cq * 4 + 3] = v4.w;
        }
        __syncthreads();

        // scores: S[m][n] = (Q[m]·K[n]) / 8, masked
        {
            float s4[4] = {0.f, 0.f, 0.f, 0.f};
            for (int k = 0; k < 64; ++k) {
                const float q = Qs[orow][k];
#pragma unroll
                for (int i = 0; i < 4; ++i) s4[i] += q * Ks[ocol + 16 * i][k];
            }
#pragma unroll
            for (int i = 0; i < 4; ++i) {
                const int n = ocol + 16 * i;
                float s = s4[i] * 0.125f;
                if (vmask[b * S_ + kt * 64 + n] == 0) s = NEGV;
                Ps[orow][n] = s;
            }
        }
        __syncthreads();

        // online softmax update for row rrow (16 threads per row)
        {
            float pv[4], pm = -1e30f;
#pragma unroll
            for (int u = 0; u < 4; ++u) {
                pv[u] = Ps[rrow][rtx * 4 + u];
                pm = fmaxf(pm, pv[u]);
            }
#pragma unroll
            for (int off = 1; off < 16; off <<= 1) pm = fmaxf(pm, __shfl_xor(pm, off));
            const float m_new = fmaxf(m_run, pm);
            const float sc = __expf(m_run - m_new);
            float tsum = 0.f;
#pragma unroll
            for (int u = 0; u < 4; ++u) {
                const float e = __expf(pv[u] - m_new);
                Ps[rrow][rtx * 4 + u] = e;
                tsum += e;
            }
#pragma unroll
            for (int off = 1; off < 16; off <<= 1) tsum += __shfl_xor(tsum, off);
            l_run = l_run * sc + tsum;
            m_run = m_new;
            if (rtx == 0) scale_s[rrow] = sc;
        }
        __syncthreads();

        // O update: acc[i] = acc[i]*scale + sum_k P[orow][k] * V[k][ocol+16i]
        {
            const float sc_o = scale_s[orow];
#pragma unroll
            for (int i = 0; i < 4; ++i) acc[i] *= sc_o;
            for (int k = 0; k < 64; ++k) {
                const float p = Ps[orow][k];
#pragma unroll
                for (int i = 0; i < 4; ++i) acc[i] += p * Vs[k][ocol + 16 * i];
            }
        }
    }

    if (rtx == 0) linv_s[rrow] = 1.0f / l_run;
    __syncthreads();
    const float linv = linv_s[orow];
#pragma unroll
    for (int i = 0; i < 4; ++i) {
        const int d = ocol + 16 * i;
        O[base_bh + (size_t)(s0 + orow) * DM_ + d] = acc[i] * linv;
    }
}

// ---------------------------------------------------------------------------
extern "C" void kernel_launch(void* const* d_in, const int* in_sizes, int n_in,
                              void* d_out, int out_size, void* d_ws, size_t ws_size,
                              hipStream_t stream)
{
    const float* x     = (const float*)d_in[0];
    const int*   vmask = (const int*)d_in[1];
    const float* pos   = (const float*)d_in[2];
    const float* Wq    = (const float*)d_in[3];
    const float* bq    = (const float*)d_in[4];
    const float* Wk    = (const float*)d_in[5];
    const float* bk    = (const float*)d_in[6];
    const float* Wv    = (const float*)d_in[7];
    const float* bv    = (const float*)d_in[8];
    const float* Wo    = (const float*)d_in[9];
    const float* bo    = (const float*)d_in[10];
    float* out = (float*)d_out;

    const int M = B_ * S_;      // 4096
    const int N = H_ * DH_;     // 1024
    const int K = DM_;          // 1024

    float* Qb = (float*)d_ws;
    float* Kb = Qb + (size_t)M * N;
    float* Vb = Kb + (size_t)M * N;
    float* Ob = Vb + (size_t)M * N;

    dim3 gemm_grid(N / 64, M / 64);
    gemm_bias_kernel<<<gemm_grid, 256, 0, stream>>>(x, Wq, bq, Qb, M, N, K);
    gemm_bias_kernel<<<gemm_grid, 256, 0, stream>>>(x, Wk, bk, Kb, M, N, K);
    gemm_bias_kernel<<<gemm_grid, 256, 0, stream>>>(x, Wv, bv, Vb, M, N, K);

    const int pairs = B_ * S_ * H_ * (DH_ / 2);
    rope_kernel<<<pairs / 256, 256, 0, stream>>>(Qb, Kb, pos);

    attn_kernel<<<B_ * H_ * (S_ / 16), 256, 0, stream>>>(Qb, Kb, Vb, vmask, Ob);

    dim3 gemm_grid2(DM_ / 64, M / 64);
    gemm_bias_kernel<<<gemm_grid2, 256, 0, stream>>>(Ob, Wo, bo, out, M, DM_, K);
}

// Round 3
// 761.385 us; speedup vs baseline: 2.4677x; 2.4677x over previous
//
#include <hip/hip_runtime.h>
#include <cstddef>
#include <cstdint>

#define B_ 2
#define S_ 2048
#define DM_ 1024
#define H_ 16
#define DH_ 64
#define NEGV (-1e12f)
// log2(e) / sqrt(DH) folded into Q at projection epilogue
#define QSCALE 0.18033688011112042f

typedef __attribute__((ext_vector_type(8))) short bf16x8;
typedef __attribute__((ext_vector_type(4))) float f32x4;

__device__ __forceinline__ unsigned short f2bf(float f) {
    union { float f; uint32_t u; } v; v.f = f;
    uint32_t u = v.u;
    u += 0x7FFF + ((u >> 16) & 1);   // round-to-nearest-even
    return (unsigned short)(u >> 16);
}

// ---------------------------------------------------------------------------
// fp32 GEMM + bias with templated epilogue.
// EPI 0: fp32 out (final projection)
// EPI 1: rope + QSCALE, bf16 out row-major   (Q)
// EPI 2: rope, bf16 out row-major            (K)
// EPI 3: bf16 out TRANSPOSED [b,h,d,s]       (V)
// ---------------------------------------------------------------------------
template <int EPI>
__global__ __launch_bounds__(256) void gemm_epi_kernel(
    const float* __restrict__ A, const float* __restrict__ W,
    const float* __restrict__ bias, void* __restrict__ Cout,
    const float* __restrict__ pos, int M, int N, int K)
{
    __shared__ float As[16][66];
    __shared__ float Bs[16][64];

    const int tid = threadIdx.x;
    const int m0 = blockIdx.y * 64;
    const int n0 = blockIdx.x * 64;
    const int tx = tid & 15;
    const int ty = tid >> 4;

    const int arow = tid >> 2, akq = tid & 3;
    const int bk   = tid >> 4, bnq = tid & 15;

    float acc[4][4];
#pragma unroll
    for (int i = 0; i < 4; ++i)
#pragma unroll
        for (int j = 0; j < 4; ++j) acc[i][j] = 0.f;

    for (int k0 = 0; k0 < K; k0 += 16) {
        const float4 a4 = *(const float4*)(A + (size_t)(m0 + arow) * K + k0 + akq * 4);
        const float4 b4 = *(const float4*)(W + (size_t)(k0 + bk) * N + n0 + bnq * 4);
        __syncthreads();
        As[akq * 4 + 0][arow] = a4.x;
        As[akq * 4 + 1][arow] = a4.y;
        As[akq * 4 + 2][arow] = a4.z;
        As[akq * 4 + 3][arow] = a4.w;
        *(float4*)&Bs[bk][bnq * 4] = b4;
        __syncthreads();
#pragma unroll
        for (int kk = 0; kk < 16; ++kk) {
            float a[4], b[4];
#pragma unroll
            for (int i = 0; i < 4; ++i) a[i] = As[kk][ty * 4 + i];
#pragma unroll
            for (int j = 0; j < 4; ++j) b[j] = Bs[kk][tx * 4 + j];
#pragma unroll
            for (int i = 0; i < 4; ++i)
#pragma unroll
                for (int j = 0; j < 4; ++j) acc[i][j] += a[i] * b[j];
        }
    }

    const float4 bia = *(const float4*)(bias + n0 + tx * 4);

    if constexpr (EPI == 0) {
        float* C = (float*)Cout;
#pragma unroll
        for (int i = 0; i < 4; ++i) {
            const int m = m0 + ty * 4 + i;
            float4 o;
            o.x = acc[i][0] + bia.x;
            o.y = acc[i][1] + bia.y;
            o.z = acc[i][2] + bia.z;
            o.w = acc[i][3] + bia.w;
            *(float4*)(C + (size_t)m * N + n0 + tx * 4) = o;
        }
    } else if constexpr (EPI == 1 || EPI == 2) {
        short* C = (short*)Cout;
#pragma unroll
        for (int i = 0; i < 4; ++i) {
            const int m = m0 + ty * 4 + i;
            const int s = m & (S_ - 1);
            // pz = (sin0, cos0, sin1, cos1) for the two rotary pairs
            const float4 pz = *(const float4*)(pos + (size_t)s * DH_ + ((n0 + tx * 4) & (DH_ - 1)));
            float v0 = acc[i][0] + bia.x, v1 = acc[i][1] + bia.y;
            float v2 = acc[i][2] + bia.z, v3 = acc[i][3] + bia.w;
            float r0 = v0 * pz.y - v1 * pz.x;
            float r1 = v1 * pz.y + v0 * pz.x;
            float r2 = v2 * pz.w - v3 * pz.z;
            float r3 = v3 * pz.w + v2 * pz.z;
            if constexpr (EPI == 1) { r0 *= QSCALE; r1 *= QSCALE; r2 *= QSCALE; r3 *= QSCALE; }
            ushort4 o;
            o.x = f2bf(r0); o.y = f2bf(r1); o.z = f2bf(r2); o.w = f2bf(r3);
            *(ushort4*)(C + (size_t)m * N + n0 + tx * 4) = o;
        }
    } else {
        // EPI 3: V transposed -> Vt[((b*H + h)*DH + d) * S + s]
        short* C = (short*)Cout;
        const int b = m0 >> 11;
        const int h = n0 >> 6;
        const int sb = (m0 & (S_ - 1)) + ty * 4;
        const float bb[4] = {bia.x, bia.y, bia.z, bia.w};
#pragma unroll
        for (int j = 0; j < 4; ++j) {
            const int d = tx * 4 + j;
            ushort4 o;
            o.x = f2bf(acc[0][j] + bb[j]);
            o.y = f2bf(acc[1][j] + bb[j]);
            o.z = f2bf(acc[2][j] + bb[j]);
            o.w = f2bf(acc[3][j] + bb[j]);
            *(ushort4*)(C + (((size_t)(b * H_ + h) * DH_ + d) * S_) + sb) = o;
        }
    }
}

// ---------------------------------------------------------------------------
// bf16 MFMA flash attention — v2: double-buffered LDS, ONE barrier per tile.
// Safety by construction: iteration kt stores (prefetched) tile kt into
// buf[kt&1], barriers, computes from buf[kt&1]. Waves are at most one barrier
// apart, and adjacent iterations write/read DIFFERENT buffers -> no
// write-after-read window exists regardless of scheduling.
// ---------------------------------------------------------------------------
__global__ __launch_bounds__(256) void attn_mfma_kernel(
    const short* __restrict__ Qb, const short* __restrict__ Kb,
    const short* __restrict__ Vt, const int* __restrict__ vmask,
    float* __restrict__ O)
{
    __shared__ short Ks[2][64 * 64];
    __shared__ short Vs[2][64 * 64];
    __shared__ float bias_s[2][64];

    const int tid  = threadIdx.x;
    const int lane = tid & 63;
    const int w    = tid >> 6;
    const int c    = lane & 15;
    const int g    = lane >> 4;

    const int bid = blockIdx.x;          // b*512 + h*32 + qc
    const int qc = bid & 31;
    const int h  = (bid >> 5) & 15;
    const int b  = bid >> 9;
    const int s0 = qc * 64;

    // Q fragments (B-operand): lane holds Q[q = lane&15][k = g*8 + j]
    bf16x8 qf[2];
    {
        const size_t qbase = ((size_t)(b * S_ + s0 + w * 16 + c)) * DM_ + h * DH_ + g * 8;
        qf[0] = *(const bf16x8*)(Qb + qbase);
        qf[1] = *(const bf16x8*)(Qb + qbase + 32);
    }

    const int kr0 = tid >> 3, kc0 = tid & 7;
    const int kr1 = kr0 + 32;
    const size_t kpan = ((size_t)b * S_) * DM_ + h * DH_;
    const size_t vpan = ((size_t)(b * H_ + h) * DH_) * S_;

    uint4 kv0, kv1, vv0, vv1;
    int mskv = 1;

#define LOAD_TILE(KT)                                                            \
    do {                                                                         \
        const size_t kg = kpan + (size_t)((KT) * 64) * DM_;                      \
        kv0 = *(const uint4*)(Kb + kg + (size_t)kr0 * DM_ + kc0 * 8);            \
        kv1 = *(const uint4*)(Kb + kg + (size_t)kr1 * DM_ + kc0 * 8);            \
        const size_t vg = vpan + (KT) * 64;                                      \
        vv0 = *(const uint4*)(Vt + vg + (size_t)kr0 * S_ + kc0 * 8);             \
        vv1 = *(const uint4*)(Vt + vg + (size_t)kr1 * S_ + kc0 * 8);             \
        if (tid < 64) mskv = vmask[b * S_ + (KT) * 64 + tid];                    \
    } while (0)

    LOAD_TILE(0);

    float m_run = -1e30f, l_run = 0.f;
    f32x4 acc_o[4];
#pragma unroll
    for (int dg = 0; dg < 4; ++dg) acc_o[dg] = (f32x4){0.f, 0.f, 0.f, 0.f};

    const int srcA = ((((g & 1) * 2) << 4) + c) * 4;
    const int srcB = ((((g & 1) * 2 + 1) << 4) + c) * 4;
    const bool hiSel = (lane >= 32);

    for (int kt = 0; kt < S_ / 64; ++kt) {
        const int cur = kt & 1;
        // ---- store prefetched tile kt into buf[cur] (other buffer than the
        // one any straggler wave may still be reading)
        *(uint4*)&Ks[cur][kr0 * 64 + ((kc0 ^ (kr0 & 7)) * 8)] = kv0;
        *(uint4*)&Ks[cur][kr1 * 64 + ((kc0 ^ (kr1 & 7)) * 8)] = kv1;
        *(uint4*)&Vs[cur][kr0 * 64 + ((kc0 ^ (kr0 & 7)) * 8)] = vv0;
        *(uint4*)&Vs[cur][kr1 * 64 + ((kc0 ^ (kr1 & 7)) * 8)] = vv1;
        if (tid < 64) bias_s[cur][tid] = mskv ? 0.f : NEGV;
        __syncthreads();   // the ONLY barrier per tile

        if (kt + 1 < S_ / 64) LOAD_TILE(kt + 1);   // overlap next loads with compute

        // ---- QK^T (swapped): acc_t[km] holds S^T[key][q=c], init with mask bias
        f32x4 acc_t[4];
#pragma unroll
        for (int km = 0; km < 4; ++km)
            acc_t[km] = *(const f32x4*)&bias_s[cur][km * 16 + g * 4];
#pragma unroll
        for (int km = 0; km < 4; ++km) {
            const int krow = km * 16 + c;
            const int swz = krow & 7;
#pragma unroll
            for (int t = 0; t < 2; ++t) {
                const bf16x8 kf = *(const bf16x8*)&Ks[cur][krow * 64 + (((t * 4 + g) ^ swz) * 8)];
                acc_t[km] = __builtin_amdgcn_mfma_f32_16x16x32_bf16(kf, qf[t], acc_t[km], 0, 0, 0);
            }
        }

        // ---- online softmax for q = lane&15 (replicated across 4 lane-groups)
        float pm = -1e30f;
#pragma unroll
        for (int km = 0; km < 4; ++km)
#pragma unroll
            for (int r = 0; r < 4; ++r) pm = fmaxf(pm, acc_t[km][r]);
        pm = fmaxf(pm, __shfl_xor(pm, 16));
        pm = fmaxf(pm, __shfl_xor(pm, 32));
        const float m_new = fmaxf(m_run, pm);
        const float sc = exp2f(m_run - m_new);

        float p[16];
        float tsum = 0.f;
#pragma unroll
        for (int km = 0; km < 4; ++km)
#pragma unroll
            for (int r = 0; r < 4; ++r) {
                const float e = exp2f(acc_t[km][r] - m_new);
                p[km * 4 + r] = e;
                tsum += e;
            }
        tsum += __shfl_xor(tsum, 16);
        tsum += __shfl_xor(tsum, 32);
        l_run = l_run * sc + tsum;
        m_run = m_new;

        uint32_t pk[4][2];
#pragma unroll
        for (int km = 0; km < 4; ++km) {
            pk[km][0] = (uint32_t)f2bf(p[km * 4 + 0]) | ((uint32_t)f2bf(p[km * 4 + 1]) << 16);
            pk[km][1] = (uint32_t)f2bf(p[km * 4 + 2]) | ((uint32_t)f2bf(p[km * 4 + 3]) << 16);
        }

        // ---- rescale O by per-row factor (rows of O live at q = g*4+r)
#pragma unroll
        for (int r = 0; r < 4; ++r) {
            const float scr = __shfl(sc, (lane & 48) | (g * 4 + r));
#pragma unroll
            for (int dg = 0; dg < 4; ++dg) acc_o[dg][r] *= scr;
        }

        // ---- P-fragment via bpermute (wave-local), then PV MFMAs
#pragma unroll
        for (int t = 0; t < 2; ++t) {
            uint32_t fw[4];
#pragma unroll
            for (int w2 = 0; w2 < 4; ++w2) {
                const int src = (w2 < 2) ? srcA : srcB;
                const uint32_t vlo = (uint32_t)__builtin_amdgcn_ds_bpermute(src, (int)pk[2 * t][w2 & 1]);
                const uint32_t vhi = (uint32_t)__builtin_amdgcn_ds_bpermute(src, (int)pk[2 * t + 1][w2 & 1]);
                fw[w2] = hiSel ? vhi : vlo;
            }
            union { uint32_t u[4]; bf16x8 v; } pf;
            pf.u[0] = fw[0]; pf.u[1] = fw[1]; pf.u[2] = fw[2]; pf.u[3] = fw[3];
#pragma unroll
            for (int dg = 0; dg < 4; ++dg) {
                const int vrow = dg * 16 + c;
                const bf16x8 vf = *(const bf16x8*)&Vs[cur][vrow * 64 + (((t * 4 + g) ^ (vrow & 7)) * 8)];
                acc_o[dg] = __builtin_amdgcn_mfma_f32_16x16x32_bf16(pf.v, vf, acc_o[dg], 0, 0, 0);
            }
        }
    }
#undef LOAD_TILE

    // ---- normalize and write O (fp32)
    const float linv = 1.0f / l_run;
#pragma unroll
    for (int r = 0; r < 4; ++r) {
        const float lr = __shfl(linv, (lane & 48) | (g * 4 + r));
        const int row = s0 + w * 16 + g * 4 + r;
        const size_t ob = ((size_t)(b * S_ + row)) * DM_ + h * DH_;
#pragma unroll
        for (int dg = 0; dg < 4; ++dg)
            O[ob + dg * 16 + c] = acc_o[dg][r] * lr;
    }
}

// ---------------------------------------------------------------------------
extern "C" void kernel_launch(void* const* d_in, const int* in_sizes, int n_in,
                              void* d_out, int out_size, void* d_ws, size_t ws_size,
                              hipStream_t stream)
{
    const float* x     = (const float*)d_in[0];
    const int*   vmask = (const int*)d_in[1];
    const float* pos   = (const float*)d_in[2];
    const float* Wq    = (const float*)d_in[3];
    const float* bq    = (const float*)d_in[4];
    const float* Wk    = (const float*)d_in[5];
    const float* bk    = (const float*)d_in[6];
    const float* Wv    = (const float*)d_in[7];
    const float* bv    = (const float*)d_in[8];
    const float* Wo    = (const float*)d_in[9];
    const float* bo    = (const float*)d_in[10];
    float* out = (float*)d_out;

    const int M = B_ * S_;      // 4096
    const int N = H_ * DH_;     // 1024
    const int K = DM_;          // 1024

    short* Qbf = (short*)d_ws;                       // 8 MB
    short* Kbf = Qbf + (size_t)M * N;                // 8 MB
    short* Vtb = Kbf + (size_t)M * N;                // 8 MB (transposed [b,h,d,s])
    float* Ob  = (float*)(Vtb + (size_t)M * N);      // 16 MB

    dim3 ggrid(N / 64, M / 64);
    gemm_epi_kernel<1><<<ggrid, 256, 0, stream>>>(x, Wq, bq, Qbf, pos, M, N, K);
    gemm_epi_kernel<2><<<ggrid, 256, 0, stream>>>(x, Wk, bk, Kbf, pos, M, N, K);
    gemm_epi_kernel<3><<<ggrid, 256, 0, stream>>>(x, Wv, bv, Vtb, pos, M, N, K);

    attn_mfma_kernel<<<B_ * H_ * (S_ / 64), 256, 0, stream>>>(Qbf, Kbf, Vtb, vmask, Ob);

    dim3 ggrid2(DM_ / 64, M / 64);
    gemm_epi_kernel<0><<<ggrid2, 256, 0, stream>>>(Ob, Wo, bo, out, nullptr, M, DM_, K);
}

// Round 4
// 198.901 us; speedup vs baseline: 9.4462x; 3.8280x over previous
//
#include <hip/hip_runtime.h>
#include <cstddef>
#include <cstdint>

#define B_ 2
#define S_ 2048
#define DM_ 1024
#define H_ 16
#define DH_ 64
#define NEGV (-1e12f)
// log2(e) / sqrt(DH) folded into Q at projection epilogue
#define QSCALE 0.18033688011112042f

typedef __attribute__((ext_vector_type(8))) short bf16x8;
typedef __attribute__((ext_vector_type(4))) float f32x4;

__device__ __forceinline__ unsigned short f2bf(float f) {
    union { float f; uint32_t u; } v; v.f = f;
    uint32_t u = v.u;
    u += 0x7FFF + ((u >> 16) & 1);   // round-to-nearest-even
    return (unsigned short)(u >> 16);
}

__device__ __forceinline__ void gload_lds16(const void* g, void* l) {
    __builtin_amdgcn_global_load_lds(
        (__attribute__((address_space(1))) void*)g,
        (__attribute__((address_space(3))) void*)l,
        16, 0, 0);
}

// ---------------------------------------------------------------------------
// x (fp32) -> bf16, flat
// ---------------------------------------------------------------------------
__global__ __launch_bounds__(256) void convx_kernel(
    const float* __restrict__ x, ushort* __restrict__ xb)
{
    const size_t i = ((size_t)blockIdx.x * 256 + threadIdx.x) * 8;
    const float4 a = *(const float4*)(x + i);
    const float4 b = *(const float4*)(x + i + 4);
    ushort4 u0, u1;
    u0.x = f2bf(a.x); u0.y = f2bf(a.y); u0.z = f2bf(a.z); u0.w = f2bf(a.w);
    u1.x = f2bf(b.x); u1.y = f2bf(b.y); u1.z = f2bf(b.z); u1.w = f2bf(b.w);
    *(ushort4*)(xb + i) = u0;
    *(ushort4*)(xb + i + 4) = u1;
}

// ---------------------------------------------------------------------------
// W[k][n] fp32 -> Wt[n][k] bf16 (64x64 LDS-tiled transpose)
// ---------------------------------------------------------------------------
__global__ __launch_bounds__(256) void wconv_kernel(
    const float* __restrict__ W, ushort* __restrict__ Wt)
{
    __shared__ float T[64][65];
    const int tid = threadIdx.x;
    const int n0 = (blockIdx.x & 15) * 64;
    const int k0 = (blockIdx.x >> 4) * 64;
    const int tr = tid >> 4, tc = tid & 15;
#pragma unroll
    for (int i = 0; i < 4; ++i) {
        const float4 v = *(const float4*)(W + (size_t)(k0 + tr + i * 16) * 1024 + n0 + tc * 4);
        T[tr + i * 16][tc * 4 + 0] = v.x;
        T[tr + i * 16][tc * 4 + 1] = v.y;
        T[tr + i * 16][tc * 4 + 2] = v.z;
        T[tr + i * 16][tc * 4 + 3] = v.w;
    }
    __syncthreads();
    const int orr = tid >> 2, oc = tid & 3;
#pragma unroll
    for (int j = 0; j < 4; ++j) {
        ushort4 u;
        u.x = f2bf(T[oc * 16 + j * 4 + 0][orr]);
        u.y = f2bf(T[oc * 16 + j * 4 + 1][orr]);
        u.z = f2bf(T[oc * 16 + j * 4 + 2][orr]);
        u.w = f2bf(T[oc * 16 + j * 4 + 3][orr]);
        *(ushort4*)(Wt + (size_t)(n0 + orr) * 1024 + k0 + oc * 16 + j * 4) = u;
    }
}

// ---------------------------------------------------------------------------
// bf16 MFMA GEMM, C = A @ Bt^T (+bias, +epilogue). A[M][1024], Bt[n][1024].
// MODE 1: fused QKV (BM=128, Ntot=3072 in 3 segments; rope epilogues, V transp)
// MODE 0: out-proj  (BM=64, N=1024, fp32 out)
// 2-phase double-buffered K-loop with global_load_lds staging (T3-min).
// MFMA convention (validated in attn kernel): mfma(X[r][k], Y[c][k]) -> D[r][c]
// with r index = (lane>>4)*4+reg, c = lane&15.
// ---------------------------------------------------------------------------
template <int MODE>
__global__ __launch_bounds__(256) void gemm_bf16(
    const ushort* __restrict__ A,
    const ushort* __restrict__ B0, const ushort* __restrict__ B1, const ushort* __restrict__ B2,
    const float* __restrict__ bias0, const float* __restrict__ bias1, const float* __restrict__ bias2,
    const float* __restrict__ pos,
    void* __restrict__ o0, void* __restrict__ o1, void* __restrict__ o2)
{
    constexpr int BM = MODE ? 128 : 64;
    constexpr int BN = 128;
    constexpr int NTN = MODE ? 24 : 8;    // n-tiles in grid
    constexpr int A_ISS = BM / 64;        // 4KB global_load_lds issues for A
    constexpr int ABYTES = BM * 64;       // bytes of A tile (BK=32 bf16 = 64B/row)
    constexpr int WM = MODE ? 2 : 1;      // waves in m
    constexpr int TM = BM / WM;           // 64
    constexpr int TN = BN / (4 / WM);     // 64 (MODE1) / 32 (MODE0)
    constexpr int MI = TM / 16;           // 4
    constexpr int NJ = TN / 16;           // 4 / 2
    constexpr int NT = DM_ / 32;          // 32 K-tiles

    __shared__ char lds[2][(BM + BN) * 64];

    const int tid  = threadIdx.x;
    const int lane = tid & 63;
    const int lc = lane & 15, lg = lane >> 4;
    const int w  = tid >> 6;
    const int wm = MODE ? (w >> 1) : 0;
    const int wn = MODE ? (w & 1) : w;

    const int ntile = blockIdx.x % NTN;
    const int mtile = blockIdx.x / NTN;
    const int m0 = mtile * BM;

    int seg = 0, nseg0 = ntile * 128;
    const ushort* Bt = B0;
    const float* biasp = bias0;
    if constexpr (MODE == 1) {
        seg = ntile >> 3;
        nseg0 = (ntile & 7) * 128;
        Bt = (seg == 0) ? B0 : (seg == 1) ? B1 : B2;
        biasp = (seg == 0) ? bias0 : (seg == 1) ? bias1 : bias2;
    }

    const int sr = tid >> 2;            // staging row within 64-row issue block
    const int sc = (tid & 3) * 8;       // staging element offset within row window
    const int wub = (tid & 0xC0) * 16;  // wave-uniform LDS byte offset (wave*1024)

#define STAGE(BUF, KT)                                                             \
    do {                                                                           \
        const int k0s = (KT) * 32;                                                 \
        char* lb = &lds[BUF][0];                                                   \
        _Pragma("unroll")                                                          \
        for (int ii = 0; ii < A_ISS; ++ii)                                         \
            gload_lds16(A + (size_t)(m0 + ii * 64 + sr) * DM_ + k0s + sc,          \
                        lb + ii * 4096 + wub);                                     \
        _Pragma("unroll")                                                          \
        for (int ii = 0; ii < 2; ++ii)                                             \
            gload_lds16(Bt + (size_t)(nseg0 + ii * 64 + sr) * DM_ + k0s + sc,      \
                        lb + ABYTES + ii * 4096 + wub);                            \
    } while (0)

    f32x4 acc[MI][NJ];
#pragma unroll
    for (int mi = 0; mi < MI; ++mi)
#pragma unroll
        for (int nj = 0; nj < NJ; ++nj) acc[mi][nj] = (f32x4){0.f, 0.f, 0.f, 0.f};

    STAGE(0, 0);

    for (int kt = 0; kt < NT; ++kt) {
        const int cur = kt & 1;
        __syncthreads();                       // drains vmcnt -> buf[cur] ready
        if (kt + 1 < NT) STAGE(cur ^ 1, kt + 1);
        const char* Ab = &lds[cur][0];
        const char* Bb = Ab + ABYTES;
        bf16x8 af[MI], bfr[NJ];
#pragma unroll
        for (int mi = 0; mi < MI; ++mi)
            af[mi] = *(const bf16x8*)(Ab + (wm * TM + mi * 16 + lc) * 64 + lg * 16);
#pragma unroll
        for (int nj = 0; nj < NJ; ++nj)
            bfr[nj] = *(const bf16x8*)(Bb + (wn * TN + nj * 16 + lc) * 64 + lg * 16);
#pragma unroll
        for (int mi = 0; mi < MI; ++mi)
#pragma unroll
            for (int nj = 0; nj < NJ; ++nj)
                acc[mi][nj] = __builtin_amdgcn_mfma_f32_16x16x32_bf16(af[mi], bfr[nj], acc[mi][nj], 0, 0, 0);
    }
#undef STAGE

    if constexpr (MODE == 0) {
        float* C = (float*)o0;
#pragma unroll
        for (int nj = 0; nj < NJ; ++nj) {
            const int n = nseg0 + wn * TN + nj * 16 + lc;
            const float bn = biasp[n];
#pragma unroll
            for (int mi = 0; mi < MI; ++mi)
#pragma unroll
                for (int r = 0; r < 4; ++r) {
                    const int m = m0 + wm * TM + mi * 16 + lg * 4 + r;
                    C[(size_t)m * DM_ + n] = acc[mi][nj][r] + bn;
                }
        }
    } else {
        if (seg < 2) {   // Q or K: bias -> rope -> (Q: scale) -> bf16 row-major
            ushort* C = (seg == 0) ? (ushort*)o0 : (ushort*)o1;
#pragma unroll
            for (int nj = 0; nj < NJ; ++nj) {
                const int n = nseg0 + wn * TN + nj * 16 + lc;
                const float bn = biasp[n];
                const int i2 = (n & 63) & ~1;
                const bool odd = (n & 1) != 0;
#pragma unroll
                for (int mi = 0; mi < MI; ++mi)
#pragma unroll
                    for (int r = 0; r < 4; ++r) {
                        const int m = m0 + wm * TM + mi * 16 + lg * 4 + r;
                        const int s = m & (S_ - 1);
                        const float2 pz = *(const float2*)(pos + (size_t)s * DH_ + i2);
                        const float v = acc[mi][nj][r] + bn;
                        const float pv = __shfl_xor(v, 1);   // partner (n^1) value
                        float ov = odd ? (v * pz.y + pv * pz.x) : (v * pz.y - pv * pz.x);
                        if (seg == 0) ov *= QSCALE;
                        C[(size_t)m * (H_ * DH_) + n] = f2bf(ov);
                    }
            }
        } else {         // V: bias -> bf16, transposed to Vt[((b*H+h)*DH+d)][s]
            ushort* C = (ushort*)o2;
#pragma unroll
            for (int nj = 0; nj < NJ; ++nj) {
                const int n = nseg0 + wn * TN + nj * 16 + lc;
                const int hh = n >> 6, dd = n & 63;
                const float bn = biasp[n];
#pragma unroll
                for (int mi = 0; mi < MI; ++mi) {
                    const int mb = m0 + wm * TM + mi * 16 + lg * 4;
                    const int bb = mb >> 11, ss = mb & (S_ - 1);
                    ushort4 u;
                    u.x = f2bf(acc[mi][nj][0] + bn);
                    u.y = f2bf(acc[mi][nj][1] + bn);
                    u.z = f2bf(acc[mi][nj][2] + bn);
                    u.w = f2bf(acc[mi][nj][3] + bn);
                    *(ushort4*)(C + ((size_t)(bb * H_ + hh) * DH_ + dd) * S_ + ss) = u;
                }
            }
        }
    }
}

// ---------------------------------------------------------------------------
// bf16 MFMA flash attention (validated round 3) — O now written as bf16.
// ---------------------------------------------------------------------------
__global__ __launch_bounds__(256) void attn_mfma_kernel(
    const short* __restrict__ Qb, const short* __restrict__ Kb,
    const short* __restrict__ Vt, const int* __restrict__ vmask,
    ushort* __restrict__ O)
{
    __shared__ short Ks[2][64 * 64];
    __shared__ short Vs[2][64 * 64];
    __shared__ float bias_s[2][64];

    const int tid  = threadIdx.x;
    const int lane = tid & 63;
    const int w    = tid >> 6;
    const int c    = lane & 15;
    const int g    = lane >> 4;

    const int bid = blockIdx.x;          // b*512 + h*32 + qc
    const int qc = bid & 31;
    const int h  = (bid >> 5) & 15;
    const int b  = bid >> 9;
    const int s0 = qc * 64;

    bf16x8 qf[2];
    {
        const size_t qbase = ((size_t)(b * S_ + s0 + w * 16 + c)) * DM_ + h * DH_ + g * 8;
        qf[0] = *(const bf16x8*)(Qb + qbase);
        qf[1] = *(const bf16x8*)(Qb + qbase + 32);
    }

    const int kr0 = tid >> 3, kc0 = tid & 7;
    const int kr1 = kr0 + 32;
    const size_t kpan = ((size_t)b * S_) * DM_ + h * DH_;
    const size_t vpan = ((size_t)(b * H_ + h) * DH_) * S_;

    uint4 kv0, kv1, vv0, vv1;
    int mskv = 1;

#define LOAD_TILE(KT)                                                            \
    do {                                                                         \
        const size_t kg = kpan + (size_t)((KT) * 64) * DM_;                      \
        kv0 = *(const uint4*)(Kb + kg + (size_t)kr0 * DM_ + kc0 * 8);            \
        kv1 = *(const uint4*)(Kb + kg + (size_t)kr1 * DM_ + kc0 * 8);            \
        const size_t vg = vpan + (KT) * 64;                                      \
        vv0 = *(const uint4*)(Vt + vg + (size_t)kr0 * S_ + kc0 * 8);             \
        vv1 = *(const uint4*)(Vt + vg + (size_t)kr1 * S_ + kc0 * 8);             \
        if (tid < 64) mskv = vmask[b * S_ + (KT) * 64 + tid];                    \
    } while (0)

    LOAD_TILE(0);

    float m_run = -1e30f, l_run = 0.f;
    f32x4 acc_o[4];
#pragma unroll
    for (int dg = 0; dg < 4; ++dg) acc_o[dg] = (f32x4){0.f, 0.f, 0.f, 0.f};

    const int srcA = ((((g & 1) * 2) << 4) + c) * 4;
    const int srcB = ((((g & 1) * 2 + 1) << 4) + c) * 4;
    const bool hiSel = (lane >= 32);

    for (int kt = 0; kt < S_ / 64; ++kt) {
        const int cur = kt & 1;
        *(uint4*)&Ks[cur][kr0 * 64 + ((kc0 ^ (kr0 & 7)) * 8)] = kv0;
        *(uint4*)&Ks[cur][kr1 * 64 + ((kc0 ^ (kr1 & 7)) * 8)] = kv1;
        *(uint4*)&Vs[cur][kr0 * 64 + ((kc0 ^ (kr0 & 7)) * 8)] = vv0;
        *(uint4*)&Vs[cur][kr1 * 64 + ((kc0 ^ (kr1 & 7)) * 8)] = vv1;
        if (tid < 64) bias_s[cur][tid] = mskv ? 0.f : NEGV;
        __syncthreads();

        if (kt + 1 < S_ / 64) LOAD_TILE(kt + 1);

        f32x4 acc_t[4];
#pragma unroll
        for (int km = 0; km < 4; ++km)
            acc_t[km] = *(const f32x4*)&bias_s[cur][km * 16 + g * 4];
#pragma unroll
        for (int km = 0; km < 4; ++km) {
            const int krow = km * 16 + c;
            const int swz = krow & 7;
#pragma unroll
            for (int t = 0; t < 2; ++t) {
                const bf16x8 kf = *(const bf16x8*)&Ks[cur][krow * 64 + (((t * 4 + g) ^ swz) * 8)];
                acc_t[km] = __builtin_amdgcn_mfma_f32_16x16x32_bf16(kf, qf[t], acc_t[km], 0, 0, 0);
            }
        }

        float pm = -1e30f;
#pragma unroll
        for (int km = 0; km < 4; ++km)
#pragma unroll
            for (int r = 0; r < 4; ++r) pm = fmaxf(pm, acc_t[km][r]);
        pm = fmaxf(pm, __shfl_xor(pm, 16));
        pm = fmaxf(pm, __shfl_xor(pm, 32));
        const float m_new = fmaxf(m_run, pm);
        const float sc = exp2f(m_run - m_new);

        float p[16];
        float tsum = 0.f;
#pragma unroll
        for (int km = 0; km < 4; ++km)
#pragma unroll
            for (int r = 0; r < 4; ++r) {
                const float e = exp2f(acc_t[km][r] - m_new);
                p[km * 4 + r] = e;
                tsum += e;
            }
        tsum += __shfl_xor(tsum, 16);
        tsum += __shfl_xor(tsum, 32);
        l_run = l_run * sc + tsum;
        m_run = m_new;

        uint32_t pk[4][2];
#pragma unroll
        for (int km = 0; km < 4; ++km) {
            pk[km][0] = (uint32_t)f2bf(p[km * 4 + 0]) | ((uint32_t)f2bf(p[km * 4 + 1]) << 16);
            pk[km][1] = (uint32_t)f2bf(p[km * 4 + 2]) | ((uint32_t)f2bf(p[km * 4 + 3]) << 16);
        }

#pragma unroll
        for (int r = 0; r < 4; ++r) {
            const float scr = __shfl(sc, (lane & 48) | (g * 4 + r));
#pragma unroll
            for (int dg = 0; dg < 4; ++dg) acc_o[dg][r] *= scr;
        }

#pragma unroll
        for (int t = 0; t < 2; ++t) {
            uint32_t fw[4];
#pragma unroll
            for (int w2 = 0; w2 < 4; ++w2) {
                const int src = (w2 < 2) ? srcA : srcB;
                const uint32_t vlo = (uint32_t)__builtin_amdgcn_ds_bpermute(src, (int)pk[2 * t][w2 & 1]);
                const uint32_t vhi = (uint32_t)__builtin_amdgcn_ds_bpermute(src, (int)pk[2 * t + 1][w2 & 1]);
                fw[w2] = hiSel ? vhi : vlo;
            }
            union { uint32_t u[4]; bf16x8 v; } pf;
            pf.u[0] = fw[0]; pf.u[1] = fw[1]; pf.u[2] = fw[2]; pf.u[3] = fw[3];
#pragma unroll
            for (int dg = 0; dg < 4; ++dg) {
                const int vrow = dg * 16 + c;
                const bf16x8 vf = *(const bf16x8*)&Vs[cur][vrow * 64 + (((t * 4 + g) ^ (vrow & 7)) * 8)];
                acc_o[dg] = __builtin_amdgcn_mfma_f32_16x16x32_bf16(pf.v, vf, acc_o[dg], 0, 0, 0);
            }
        }
        __syncthreads();
    }
#undef LOAD_TILE

    const float linv = 1.0f / l_run;
#pragma unroll
    for (int r = 0; r < 4; ++r) {
        const float lr = __shfl(linv, (lane & 48) | (g * 4 + r));
        const int row = s0 + w * 16 + g * 4 + r;
        const size_t ob = ((size_t)(b * S_ + row)) * DM_ + h * DH_;
#pragma unroll
        for (int dg = 0; dg < 4; ++dg)
            O[ob + dg * 16 + c] = f2bf(acc_o[dg][r] * lr);
    }
}

// ---------------------------------------------------------------------------
extern "C" void kernel_launch(void* const* d_in, const int* in_sizes, int n_in,
                              void* d_out, int out_size, void* d_ws, size_t ws_size,
                              hipStream_t stream)
{
    const float* x     = (const float*)d_in[0];
    const int*   vmask = (const int*)d_in[1];
    const float* pos   = (const float*)d_in[2];
    const float* Wq    = (const float*)d_in[3];
    const float* bq    = (const float*)d_in[4];
    const float* Wk    = (const float*)d_in[5];
    const float* bk    = (const float*)d_in[6];
    const float* Wv    = (const float*)d_in[7];
    const float* bv    = (const float*)d_in[8];
    const float* Wo    = (const float*)d_in[9];
    const float* bo    = (const float*)d_in[10];
    float* out = (float*)d_out;

    const size_t MN = (size_t)(B_ * S_) * (H_ * DH_);   // 4M

    ushort* xb  = (ushort*)d_ws;          // 8 MB
    ushort* Wtq = xb + MN;                // 2 MB each
    ushort* Wtk = Wtq + 1024 * 1024;
    ushort* Wtv = Wtk + 1024 * 1024;
    ushort* Wto = Wtv + 1024 * 1024;
    ushort* Qb  = Wto + 1024 * 1024;      // 8 MB each
    ushort* Kb  = Qb + MN;
    ushort* Vt  = Kb + MN;
    ushort* Ob  = Vt + MN;

    convx_kernel<<<(int)(MN / 2048), 256, 0, stream>>>(x, xb);
    wconv_kernel<<<256, 256, 0, stream>>>(Wq, Wtq);
    wconv_kernel<<<256, 256, 0, stream>>>(Wk, Wtk);
    wconv_kernel<<<256, 256, 0, stream>>>(Wv, Wtv);
    wconv_kernel<<<256, 256, 0, stream>>>(Wo, Wto);

    // fused QKV: grid = (4096/128) m-tiles x 24 n-tiles = 768 blocks (3/CU)
    gemm_bf16<1><<<768, 256, 0, stream>>>(xb, Wtq, Wtk, Wtv, bq, bk, bv, pos,
                                          (void*)Qb, (void*)Kb, (void*)Vt);

    attn_mfma_kernel<<<B_ * H_ * (S_ / 64), 256, 0, stream>>>(
        (const short*)Qb, (const short*)Kb, (const short*)Vt, vmask, Ob);

    // out-proj: grid = (4096/64) x 8 = 512 blocks (2/CU)
    gemm_bf16<0><<<512, 256, 0, stream>>>(Ob, Wto, nullptr, nullptr, bo, nullptr, nullptr,
                                          nullptr, (void*)out, nullptr, nullptr);
}